// Round 1
// baseline (668.278 us; speedup 1.0000x reference)
//
#include <hip/hip_runtime.h>
#include <hip/hip_bf16.h>

typedef __bf16 bf16;
typedef __bf16 bf16x8 __attribute__((ext_vector_type(8)));
typedef __bf16 bf16x4 __attribute__((ext_vector_type(4)));
typedef float  f32x4  __attribute__((ext_vector_type(4)));

#define GLD16(g, l) __builtin_amdgcn_global_load_lds(                        \
    (const __attribute__((address_space(1))) void*)(g),                      \
    (__attribute__((address_space(3))) void*)(l), 16, 0, 0)

// ---------------------------------------------------------------------------
// NT GEMM: C[m,n] = alpha * sum_k A[m,k]*B[n,k] (+ bias[n]) (+ relu)
// A: [M,K] row-major (lda), B: [N,K] row-major (ldb), C bf16 (ldc).
// Batched via gridDim.z: z -> (zo = z/inner, zi = z%inner), per-tensor strides.
// Requires M%BM==0, N%BN==0, K%32==0 (true for every call in this pipeline).
// ---------------------------------------------------------------------------
template<int BM, int BN, int MFR, int NFR>
__global__ __launch_bounds__(256)
void gemm_nt(const bf16* __restrict__ A, const bf16* __restrict__ B,
             bf16* __restrict__ C, const float* __restrict__ bias,
             int K, int lda, int ldb, int ldc,
             int inner,
             long long aOut, long long aIn,
             long long bOut, long long bIn,
             long long cOut, long long cIn,
             float alpha, int relu)
{
    const int z  = blockIdx.z;
    const int zo = z / inner;
    const int zi = z - zo * inner;
    A += (long long)zo * aOut + (long long)zi * aIn;
    B += (long long)zo * bOut + (long long)zi * bIn;
    C += (long long)zo * cOut + (long long)zi * cIn;

    const int tm = blockIdx.y * BM;
    const int tn = blockIdx.x * BN;

    __shared__ __align__(16) bf16 smem[(BM + BN) * 32];
    bf16* As = smem;
    bf16* Bs = smem + BM * 32;

    const int tid  = threadIdx.x;
    const int lane = tid & 63;
    const int wid  = tid >> 6;
    const int wr   = wid >> 1;   // wave row (2)
    const int wc   = wid & 1;    // wave col (2)

    f32x4 acc[MFR][NFR];
#pragma unroll
    for (int i = 0; i < MFR; ++i)
#pragma unroll
        for (int j = 0; j < NFR; ++j) acc[i][j] = (f32x4){0.f, 0.f, 0.f, 0.f};

    const int lrow = lane >> 2;        // 0..15: row within a 16-row chunk
    const int lk   = (lane & 3) * 8;   // k element offset (4 chunks of 8 bf16)
    const int lr   = lane & 15;        // mfma row/col within 16
    const int q8   = (lane >> 4) * 8;  // mfma k chunk

    for (int kt = 0; kt < K; kt += 32) {
        // ---- stage A tile [BM][32] ----
#pragma unroll
        for (int jj = 0; jj < BM / 64; ++jj) {
            const int R0 = (wid * (BM / 64) + jj) * 16;      // wave-uniform
            const bf16* g = A + (long long)(tm + R0 + lrow) * lda + kt + lk;
            GLD16(g, As + R0 * 32);
        }
        // ---- stage B tile [BN][32] ----
#pragma unroll
        for (int jj = 0; jj < BN / 64; ++jj) {
            const int R0 = (wid * (BN / 64) + jj) * 16;
            const bf16* g = B + (long long)(tn + R0 + lrow) * ldb + kt + lk;
            GLD16(g, Bs + R0 * 32);
        }
        __syncthreads();   // drains vmcnt (global_load_lds) + barrier

        bf16x8 af[MFR], bfr[NFR];
#pragma unroll
        for (int i = 0; i < MFR; ++i)
            af[i] = *(const bf16x8*)(As + (wr * MFR * 16 + i * 16 + lr) * 32 + q8);
#pragma unroll
        for (int j = 0; j < NFR; ++j)
            bfr[j] = *(const bf16x8*)(Bs + (wc * NFR * 16 + j * 16 + lr) * 32 + q8);
#pragma unroll
        for (int i = 0; i < MFR; ++i)
#pragma unroll
            for (int j = 0; j < NFR; ++j)
                acc[i][j] = __builtin_amdgcn_mfma_f32_16x16x32_bf16(
                    af[i], bfr[j], acc[i][j], 0, 0, 0);
        __syncthreads();
    }

    // epilogue: C/D layout col=lane&15, row=(lane>>4)*4+reg  [m89-verified]
#pragma unroll
    for (int i = 0; i < MFR; ++i) {
#pragma unroll
        for (int j = 0; j < NFR; ++j) {
#pragma unroll
            for (int r = 0; r < 4; ++r) {
                const int mm = tm + wr * MFR * 16 + i * 16 + (lane >> 4) * 4 + r;
                const int nn = tn + wc * NFR * 16 + j * 16 + (lane & 15);
                float v = acc[i][j][r] * alpha;
                if (bias) v += bias[nn];
                if (relu) v = fmaxf(v, 0.f);
                C[(long long)mm * ldc + nn] = (bf16)v;
            }
        }
    }
}

// ---------------------------------------------------------------------------
// x + sinusoidal PE, fp32 -> bf16.  [16384,768]; one thread per 4 elems.
// ---------------------------------------------------------------------------
__global__ __launch_bounds__(256)
void pe_cast_kernel(const float* __restrict__ x, bf16* __restrict__ out)
{
    const int idx4 = (blockIdx.x * 256 + threadIdx.x) * 4;
    const int d    = idx4 % 768;
    const int row  = idx4 / 768;
    const int s    = row & 511;
    const float ksc = -0.034603417655076f;  // -2*log2(10000)/768
    const float4 xv = *(const float4*)(x + (long long)idx4);
    float a0 = (float)s * exp2f((float)d * ksc);
    float a1 = (float)s * exp2f((float)(d + 2) * ksc);
    float s0, c0, s1, c1;
    sincosf(a0, &s0, &c0);
    sincosf(a1, &s1, &c1);
    bf16x4 o;
    o[0] = (bf16)(xv.x + s0);
    o[1] = (bf16)(xv.y + c0);
    o[2] = (bf16)(xv.z + s1);
    o[3] = (bf16)(xv.w + c1);
    *(bf16x4*)(out + (long long)idx4) = o;
}

// flat fp32 -> bf16 cast, 4 elems/thread
__global__ __launch_bounds__(256)
void cast_kernel(const float* __restrict__ src, bf16* __restrict__ dst, int n4)
{
    const int i = blockIdx.x * 256 + threadIdx.x;
    if (i < n4) {
        const float4 v = *(const float4*)(src + (long long)i * 4);
        bf16x4 o;
        o[0] = (bf16)v.x; o[1] = (bf16)v.y; o[2] = (bf16)v.z; o[3] = (bf16)v.w;
        *(bf16x4*)(dst + (long long)i * 4) = o;
    }
}

// 768x768 transpose + cast: dst[c][r] = src[r][c]
__global__ __launch_bounds__(256)
void cast_t_kernel(const float* __restrict__ src, bf16* __restrict__ dst)
{
    __shared__ bf16 t[32][33];
    const int r0 = blockIdx.y * 32, c0 = blockIdx.x * 32;
    const int tr = threadIdx.x >> 5, tc = threadIdx.x & 31;
#pragma unroll
    for (int k = 0; k < 4; ++k) {
        const int r = tr + k * 8;
        t[r][tc] = (bf16)src[(long long)(r0 + r) * 768 + c0 + tc];
    }
    __syncthreads();
#pragma unroll
    for (int k = 0; k < 4; ++k) {
        const int c = tr + k * 8;
        dst[(long long)(c0 + c) * 768 + r0 + tc] = t[tc][c];
    }
}

// V2 [16384, cols 1536..2304 of 3072] -> VT [128][192][512]
__global__ __launch_bounds__(256)
void transpose_v_kernel(const bf16* __restrict__ qkvx, bf16* __restrict__ vt)
{
    __shared__ __align__(16) bf16 t[64][80];
    const int z  = blockIdx.z;          // b*4+h
    const int b  = z >> 2, h = z & 3;
    const int s0 = blockIdx.y * 64;
    const int hd0 = blockIdx.x * 64;
    const int tt = threadIdx.x;
    const int sl = tt >> 2;
    const int cc = (tt & 3) * 16;
    const bf16* src = qkvx + (long long)(b * 512 + s0 + sl) * 3072 + 1536 + h * 192 + hd0 + cc;
    bf16x8 v0 = *(const bf16x8*)(src);
    bf16x8 v1 = *(const bf16x8*)(src + 8);
#pragma unroll
    for (int i = 0; i < 8; ++i) { t[sl][cc + i] = v0[i]; t[sl][cc + 8 + i] = v1[i]; }
    __syncthreads();
    const int hl = tt >> 2;
    bf16* dst = vt + ((long long)z * 192 + hd0 + hl) * 512 + s0 + cc;
    bf16x8 o0, o1;
#pragma unroll
    for (int i = 0; i < 8; ++i) { o0[i] = t[cc + i][hl]; o1[i] = t[cc + 8 + i][hl]; }
    *(bf16x8*)dst = o0;
    *(bf16x8*)(dst + 8) = o1;
}

// in-place row softmax over 512 bf16; one wave per row
__global__ __launch_bounds__(256)
void softmax_kernel(bf16* __restrict__ S)
{
    const int row  = blockIdx.x * 4 + (threadIdx.x >> 6);
    const int lane = threadIdx.x & 63;
    bf16* p = S + (long long)row * 512 + lane * 8;
    bf16x8 v8 = *(bf16x8*)p;
    float v[8];
#pragma unroll
    for (int i = 0; i < 8; ++i) v[i] = (float)v8[i];
    float m = v[0];
#pragma unroll
    for (int i = 1; i < 8; ++i) m = fmaxf(m, v[i]);
    for (int off = 32; off; off >>= 1) m = fmaxf(m, __shfl_xor(m, off));
    float sum = 0.f;
#pragma unroll
    for (int i = 0; i < 8; ++i) { v[i] = __expf(v[i] - m); sum += v[i]; }
    for (int off = 32; off; off >>= 1) sum += __shfl_xor(sum, off);
    const float r = 1.0f / sum;
    bf16x8 o;
#pragma unroll
    for (int i = 0; i < 8; ++i) o[i] = (bf16)(v[i] * r);
    *(bf16x8*)p = o;
}

// LayerNorm(a_row + b_row) * g + beta -> o   (768 cols, 3 per thread)
// NOTE: no __restrict__ — LN2 runs in-place (b == o).
__global__ __launch_bounds__(256)
void ln_kernel(const bf16* a, int lda_, const bf16* b, int ldb_,
               bf16* o, int ldo, const float* g, const float* be)
{
    const int row = blockIdx.x;
    const int t   = threadIdx.x;
    const bf16* pa = a + (long long)row * lda_;
    const bf16* pb = b + (long long)row * ldb_;
    float xv[3];
#pragma unroll
    for (int k = 0; k < 3; ++k) {
        const int d = t + k * 256;
        xv[k] = (float)pa[d] + (float)pb[d];
    }
    float s1 = xv[0] + xv[1] + xv[2];
    float s2 = xv[0]*xv[0] + xv[1]*xv[1] + xv[2]*xv[2];
    for (int off = 32; off; off >>= 1) {
        s1 += __shfl_xor(s1, off);
        s2 += __shfl_xor(s2, off);
    }
    __shared__ float red[8];
    const int wid = t >> 6, lane = t & 63;
    if (lane == 0) { red[wid] = s1; red[4 + wid] = s2; }
    __syncthreads();
    s1 = red[0] + red[1] + red[2] + red[3];
    s2 = red[4] + red[5] + red[6] + red[7];
    const float mu  = s1 * (1.0f / 768.0f);
    const float var = s2 * (1.0f / 768.0f) - mu * mu;
    const float rs  = rsqrtf(var + 1e-5f);
    bf16* po = o + (long long)row * ldo;
#pragma unroll
    for (int k = 0; k < 3; ++k) {
        const int d = t + k * 256;
        po[d] = (bf16)(((xv[k] - mu) * rs) * g[d] + be[d]);
    }
}

// fused bias: bcat[n<2304] = in_proj_b[n] + sum_h in_proj_w[n,h]*b_src[h];
//             bcat[2304+n] = bx[n]
__global__ __launch_bounds__(256)
void make_bias_kernel(const float* __restrict__ inpw, const float* __restrict__ inpb,
                      const float* __restrict__ bq, const float* __restrict__ bk,
                      const float* __restrict__ bv, const float* __restrict__ bx,
                      float* __restrict__ bcat)
{
    const int n = blockIdx.x * 256 + threadIdx.x;
    if (n < 2304) {
        const int zsec = n / 768;
        const float* bb = (zsec == 0) ? bq : ((zsec == 1) ? bk : bv);
        float s = inpb[n];
        const float* wrow = inpw + (long long)n * 768;
        for (int d = 0; d < 768; ++d) s += wrow[d] * bb[d];
        bcat[n] = s;
    } else {
        bcat[n] = bx[n - 2304];
    }
}

// per-batch: red[d] = sum_s x2[b,s,d]; out[b,c] = sum_d red[d]*w[c,d] + bias[c]
__global__ __launch_bounds__(256)
void reduce_fc2_kernel(const bf16* __restrict__ x2, const float* __restrict__ w,
                       const float* __restrict__ bias, float* __restrict__ out)
{
    const int b = blockIdx.x, t = threadIdx.x;
    float a0 = 0.f, a1 = 0.f, a2 = 0.f;
    const bf16* base = x2 + (long long)b * 512 * 3072;
    for (int s = 0; s < 512; ++s) {
        const bf16* row = base + (long long)s * 3072;
        a0 += (float)row[t];
        a1 += (float)row[t + 256];
        a2 += (float)row[t + 512];
    }
    __shared__ float os[10];
    if (t < 10) os[t] = 0.f;
    __syncthreads();
    for (int c = 0; c < 10; ++c) {
        float p = w[c * 768 + t] * a0 + w[c * 768 + t + 256] * a1 + w[c * 768 + t + 512] * a2;
        for (int off = 32; off; off >>= 1) p += __shfl_xor(p, off);
        if ((t & 63) == 0) atomicAdd(&os[c], p);
    }
    __syncthreads();
    if (t < 10) out[b * 10 + t] = os[t] + bias[t];
}

// ---------------------------------------------------------------------------
// workspace layout (bytes)
// ---------------------------------------------------------------------------
static const size_t OFF_XPE  = 0;
static const size_t OFF_WCAT = OFF_XPE  + (size_t)16384 * 768 * 2;
static const size_t OFF_WT3  = OFF_WCAT + (size_t)3072 * 768 * 2;
static const size_t OFF_INPJ = OFF_WT3  + (size_t)3 * 768 * 768 * 2;
static const size_t OFF_WOUT = OFF_INPJ + (size_t)2304 * 768 * 2;
static const size_t OFF_WF1A = OFF_WOUT + (size_t)768 * 768 * 2;
static const size_t OFF_WF1B = OFF_WF1A + (size_t)768 * 768 * 2;
static const size_t OFF_BCAT = OFF_WF1B + (size_t)768 * 768 * 2;
static const size_t OFF_QKVX = OFF_BCAT + (size_t)3072 * 4;
static const size_t OFF_VT   = OFF_QKVX + (size_t)16384 * 3072 * 2;
static const size_t OFF_S    = OFF_VT   + (size_t)128 * 192 * 512 * 2;
static const size_t OFF_X1   = OFF_S    + (size_t)128 * 512 * 512 * 2;
// total = OFF_X1 + 16384*768*2 = 258,617,344 bytes

extern "C" void kernel_launch(void* const* d_in, const int* in_sizes, int n_in,
                              void* d_out, int out_size, void* d_ws, size_t ws_size,
                              hipStream_t stream)
{
    const float* x     = (const float*)d_in[0];
    const float* wq    = (const float*)d_in[1];
    const float* bq    = (const float*)d_in[2];
    const float* wk    = (const float*)d_in[3];
    const float* bk    = (const float*)d_in[4];
    const float* wv    = (const float*)d_in[5];
    const float* bv    = (const float*)d_in[6];
    const float* wx    = (const float*)d_in[7];
    const float* bx    = (const float*)d_in[8];
    const float* inpw  = (const float*)d_in[9];
    const float* inpb  = (const float*)d_in[10];
    const float* woutp = (const float*)d_in[11];
    const float* boutp = (const float*)d_in[12];
    const float* wf1a  = (const float*)d_in[13];
    const float* bf1a  = (const float*)d_in[14];
    const float* wf1b  = (const float*)d_in[15];
    const float* bf1b  = (const float*)d_in[16];
    const float* lng   = (const float*)d_in[17];
    const float* lnb   = (const float*)d_in[18];
    const float* wfc2  = (const float*)d_in[19];
    const float* bfc2  = (const float*)d_in[20];
    float* out = (float*)d_out;

    char* ws = (char*)d_ws;
    bf16*  XPE  = (bf16*)(ws + OFF_XPE);
    bf16*  WCAT = (bf16*)(ws + OFF_WCAT);
    bf16*  WT3  = (bf16*)(ws + OFF_WT3);
    bf16*  INPJ = (bf16*)(ws + OFF_INPJ);
    bf16*  WOUT = (bf16*)(ws + OFF_WOUT);
    bf16*  WF1A = (bf16*)(ws + OFF_WF1A);
    bf16*  WF1B = (bf16*)(ws + OFF_WF1B);
    float* BCAT = (float*)(ws + OFF_BCAT);
    bf16*  QKVX = (bf16*)(ws + OFF_QKVX);
    bf16*  VT   = (bf16*)(ws + OFF_VT);
    bf16*  Smat = (bf16*)(ws + OFF_S);
    bf16*  X1   = (bf16*)(ws + OFF_X1);

    // ---- weight prep ----
    cast_t_kernel<<<dim3(24, 24), 256, 0, stream>>>(wq, WT3);
    cast_t_kernel<<<dim3(24, 24), 256, 0, stream>>>(wk, WT3 + 589824);
    cast_t_kernel<<<dim3(24, 24), 256, 0, stream>>>(wv, WT3 + 2 * 589824);
    cast_kernel<<<1728, 256, 0, stream>>>(inpw, INPJ, 442368);
    cast_kernel<<<576, 256, 0, stream>>>(woutp, WOUT, 147456);
    cast_kernel<<<576, 256, 0, stream>>>(wf1a, WF1A, 147456);
    cast_kernel<<<576, 256, 0, stream>>>(wf1b, WF1B, 147456);
    cast_kernel<<<576, 256, 0, stream>>>(wx, WCAT + (size_t)2304 * 768, 147456);
    // W_eff[z] = in_proj_w[z] @ w{q,k,v}  (batched, NT with transposed first-layer weights)
    gemm_nt<128, 128, 4, 4><<<dim3(6, 6, 3), 256, 0, stream>>>(
        INPJ, WT3, WCAT, nullptr, 768, 768, 768, 768,
        1, 589824, 0, 589824, 0, 589824, 0, 1.0f, 0);
    make_bias_kernel<<<12, 256, 0, stream>>>(inpw, inpb, bq, bk, bv, bx, BCAT);

    // ---- activations ----
    pe_cast_kernel<<<12288, 256, 0, stream>>>(x, XPE);

    // QKVX = XPE @ WCAT^T + BCAT   -> [16384, 3072] = Q2|K2|V2|XR
    gemm_nt<128, 128, 4, 4><<<dim3(24, 128, 1), 256, 0, stream>>>(
        XPE, WCAT, QKVX, BCAT, 768, 768, 768, 3072,
        1, 0, 0, 0, 0, 0, 0, 1.0f, 0);

    transpose_v_kernel<<<dim3(3, 8, 128), 256, 0, stream>>>(QKVX, VT);

    // scores = Q2 K2^T / sqrt(192), batched over (b,h)
    gemm_nt<128, 128, 4, 4><<<dim3(4, 4, 128), 256, 0, stream>>>(
        QKVX, QKVX + 768, Smat, nullptr, 192, 3072, 3072, 512,
        4, 1572864, 192, 1572864, 192, 1048576, 262144, 0.0721687836f, 0);

    softmax_kernel<<<16384, 256, 0, stream>>>(Smat);

    // ctx = P @ V  (VT is [hd, s] so this is NT), writes into Q2 region
    gemm_nt<128, 64, 4, 2><<<dim3(3, 4, 128), 256, 0, stream>>>(
        Smat, VT, QKVX, nullptr, 512, 512, 512, 3072,
        4, 1048576, 262144, 393216, 98304, 1572864, 192, 1.0f, 0);

    // attn_out = ctx @ out_proj^T + b, writes into K2 region
    gemm_nt<128, 128, 4, 4><<<dim3(6, 128, 1), 256, 0, stream>>>(
        QKVX, WOUT, QKVX + 768, boutp, 768, 3072, 768, 3072,
        1, 0, 0, 0, 0, 0, 0, 1.0f, 0);

    // x1 = LN(XR + attn_out)
    ln_kernel<<<16384, 256, 0, stream>>>(QKVX + 2304, 3072, QKVX + 768, 3072,
                                         X1, 768, lng, lnb);

    // h1 = relu(x1 @ fc1a^T + b) -> V2 region
    gemm_nt<128, 128, 4, 4><<<dim3(6, 128, 1), 256, 0, stream>>>(
        X1, WF1A, QKVX + 1536, bf1a, 768, 768, 768, 3072,
        1, 0, 0, 0, 0, 0, 0, 1.0f, 1);

    // ffn = h1 @ fc1b^T + b -> XR region
    gemm_nt<128, 128, 4, 4><<<dim3(6, 128, 1), 256, 0, stream>>>(
        QKVX + 1536, WF1B, QKVX + 2304, bf1b, 768, 3072, 768, 3072,
        1, 0, 0, 0, 0, 0, 0, 1.0f, 0);

    // x2 = LN(x1 + ffn), in-place over ffn region
    ln_kernel<<<16384, 256, 0, stream>>>(X1, 768, QKVX + 2304, 3072,
                                         QKVX + 2304, 3072, lng, lnb);

    // out = (sum_s x2) @ fc2^T + b
    reduce_fc2_kernel<<<32, 256, 0, stream>>>(QKVX + 2304, wfc2, bfc2, out);
}

// Round 2
// 627.967 us; speedup vs baseline: 1.0642x; 1.0642x over previous
//
#include <hip/hip_runtime.h>
#include <hip/hip_bf16.h>

typedef __bf16 bf16;
typedef __bf16 bf16x8 __attribute__((ext_vector_type(8)));
typedef __bf16 bf16x4 __attribute__((ext_vector_type(4)));
typedef float  f32x4  __attribute__((ext_vector_type(4)));

#define GLD16(g, l) __builtin_amdgcn_global_load_lds(                        \
    (const __attribute__((address_space(1))) void*)(g),                      \
    (__attribute__((address_space(3))) void*)(l), 16, 0, 0)

// ---------------------------------------------------------------------------
// NT GEMM: C[m,n] = alpha * sum_k A[m,k]*B[n,k] (+ bias[n]) (+ relu)
// LDS k-chunk XOR swizzle: physical 16B chunk p at row r holds global chunk
// p ^ ((r>>1)&3).  Fragment-read bank slot = 4*(r&1) + (q ^ ((r>>1)&3))
// covers all 8 four-bank slots -> 2 lanes/bank (free, m136) instead of the
// unswizzled 8-way conflict (stride 64 B = 16 banks).
// ---------------------------------------------------------------------------
template<int BM, int BN, int MFR, int NFR>
__global__ __launch_bounds__(256)
void gemm_nt(const bf16* __restrict__ A, const bf16* __restrict__ B,
             bf16* __restrict__ C, const float* __restrict__ bias,
             int K, int lda, int ldb, int ldc,
             int inner,
             long long aOut, long long aIn,
             long long bOut, long long bIn,
             long long cOut, long long cIn,
             float alpha, int relu)
{
    const int z  = blockIdx.z;
    const int zo = z / inner;
    const int zi = z - zo * inner;
    A += (long long)zo * aOut + (long long)zi * aIn;
    B += (long long)zo * bOut + (long long)zi * bIn;
    C += (long long)zo * cOut + (long long)zi * cIn;

    const int tm = blockIdx.y * BM;
    const int tn = blockIdx.x * BN;

    __shared__ __align__(16) bf16 smem[(BM + BN) * 32];
    bf16* As = smem;
    bf16* Bs = smem + BM * 32;

    const int tid  = threadIdx.x;
    const int lane = tid & 63;
    const int wid  = tid >> 6;
    const int wr   = wid >> 1;   // wave row (2)
    const int wc   = wid & 1;    // wave col (2)

    f32x4 acc[MFR][NFR];
#pragma unroll
    for (int i = 0; i < MFR; ++i)
#pragma unroll
        for (int j = 0; j < NFR; ++j) acc[i][j] = (f32x4){0.f, 0.f, 0.f, 0.f};

    const int lrow = lane >> 2;                                  // 0..15
    const int lk   = (((lane & 3) ^ ((lrow >> 1) & 3)) * 8);     // swizzled global k-chunk
    const int lr   = lane & 15;                                  // mfma row/col
    const int qp   = (((lane >> 4) ^ ((lr >> 1) & 3)) * 8);      // swizzled phys chunk

    for (int kt = 0; kt < K; kt += 32) {
        // ---- stage A tile [BM][32] ----
#pragma unroll
        for (int jj = 0; jj < BM / 64; ++jj) {
            const int R0 = (wid * (BM / 64) + jj) * 16;      // wave-uniform
            const bf16* g = A + (long long)(tm + R0 + lrow) * lda + kt + lk;
            GLD16(g, As + R0 * 32);
        }
        // ---- stage B tile [BN][32] ----
#pragma unroll
        for (int jj = 0; jj < BN / 64; ++jj) {
            const int R0 = (wid * (BN / 64) + jj) * 16;
            const bf16* g = B + (long long)(tn + R0 + lrow) * ldb + kt + lk;
            GLD16(g, Bs + R0 * 32);
        }
        __syncthreads();   // drains vmcnt (global_load_lds) + barrier

        bf16x8 af[MFR], bfr[NFR];
#pragma unroll
        for (int i = 0; i < MFR; ++i)
            af[i] = *(const bf16x8*)(As + (wr * MFR * 16 + i * 16 + lr) * 32 + qp);
#pragma unroll
        for (int j = 0; j < NFR; ++j)
            bfr[j] = *(const bf16x8*)(Bs + (wc * NFR * 16 + j * 16 + lr) * 32 + qp);
#pragma unroll
        for (int i = 0; i < MFR; ++i)
#pragma unroll
            for (int j = 0; j < NFR; ++j)
                acc[i][j] = __builtin_amdgcn_mfma_f32_16x16x32_bf16(
                    af[i], bfr[j], acc[i][j], 0, 0, 0);
        __syncthreads();
    }

    // epilogue: C/D layout col=lane&15, row=(lane>>4)*4+reg  [m89-verified]
#pragma unroll
    for (int i = 0; i < MFR; ++i) {
#pragma unroll
        for (int j = 0; j < NFR; ++j) {
#pragma unroll
            for (int r = 0; r < 4; ++r) {
                const int mm = tm + wr * MFR * 16 + i * 16 + (lane >> 4) * 4 + r;
                const int nn = tn + wc * NFR * 16 + j * 16 + (lane & 15);
                float v = acc[i][j][r] * alpha;
                if (bias) v += bias[nn];
                if (relu) v = fmaxf(v, 0.f);
                C[(long long)mm * ldc + nn] = (bf16)v;
            }
        }
    }
}

// ---------------------------------------------------------------------------
// PE table [512][768] fp32 (computed once, L2/L3-resident for the add pass)
// ---------------------------------------------------------------------------
__global__ __launch_bounds__(256)
void pe_table_kernel(float* __restrict__ pe)
{
    const int idx4 = (blockIdx.x * 256 + threadIdx.x) * 4;   // over 512*768
    const int d    = idx4 % 768;
    const int s    = idx4 / 768;
    const float ksc = -0.034603417655076f;  // -2*log2(10000)/768
    float a0 = (float)s * exp2f((float)d * ksc);
    float a1 = (float)s * exp2f((float)(d + 2) * ksc);
    float s0, c0, s1, c1;
    sincosf(a0, &s0, &c0);
    sincosf(a1, &s1, &c1);
    *(float4*)(pe + idx4) = make_float4(s0, c0, s1, c1);
}

// x + PE, fp32 -> bf16.  [16384,768]; one thread per 4 elems.
__global__ __launch_bounds__(256)
void pe_cast_kernel(const float* __restrict__ x, const float* __restrict__ pe,
                    bf16* __restrict__ out)
{
    const int idx4 = (blockIdx.x * 256 + threadIdx.x) * 4;
    const int d    = idx4 % 768;
    const int row  = idx4 / 768;
    const int s    = row & 511;
    const float4 xv = *(const float4*)(x + (long long)idx4);
    const float4 pv = *(const float4*)(pe + s * 768 + d);
    bf16x4 o;
    o[0] = (bf16)(xv.x + pv.x);
    o[1] = (bf16)(xv.y + pv.y);
    o[2] = (bf16)(xv.z + pv.z);
    o[3] = (bf16)(xv.w + pv.w);
    *(bf16x4*)(out + (long long)idx4) = o;
}

// flat fp32 -> bf16 cast, 4 elems/thread
__global__ __launch_bounds__(256)
void cast_kernel(const float* __restrict__ src, bf16* __restrict__ dst, int n4)
{
    const int i = blockIdx.x * 256 + threadIdx.x;
    if (i < n4) {
        const float4 v = *(const float4*)(src + (long long)i * 4);
        bf16x4 o;
        o[0] = (bf16)v.x; o[1] = (bf16)v.y; o[2] = (bf16)v.z; o[3] = (bf16)v.w;
        *(bf16x4*)(dst + (long long)i * 4) = o;
    }
}

// 768x768 transpose + cast: dst[c][r] = src[r][c]
__global__ __launch_bounds__(256)
void cast_t_kernel(const float* __restrict__ src, bf16* __restrict__ dst)
{
    __shared__ bf16 t[32][33];
    const int r0 = blockIdx.y * 32, c0 = blockIdx.x * 32;
    const int tr = threadIdx.x >> 5, tc = threadIdx.x & 31;
#pragma unroll
    for (int k = 0; k < 4; ++k) {
        const int r = tr + k * 8;
        t[r][tc] = (bf16)src[(long long)(r0 + r) * 768 + c0 + tc];
    }
    __syncthreads();
#pragma unroll
    for (int k = 0; k < 4; ++k) {
        const int c = tr + k * 8;
        dst[(long long)(c0 + c) * 768 + r0 + tc] = t[tc][c];
    }
}

// V2 [16384, cols 1536..2304 of 3072] -> VT [128][192][512]
__global__ __launch_bounds__(256)
void transpose_v_kernel(const bf16* __restrict__ qkvx, bf16* __restrict__ vt)
{
    __shared__ __align__(16) bf16 t[64][80];
    const int z  = blockIdx.z;          // b*4+h
    const int b  = z >> 2, h = z & 3;
    const int s0 = blockIdx.y * 64;
    const int hd0 = blockIdx.x * 64;
    const int tt = threadIdx.x;
    const int sl = tt >> 2;
    const int cc = (tt & 3) * 16;
    const bf16* src = qkvx + (long long)(b * 512 + s0 + sl) * 3072 + 1536 + h * 192 + hd0 + cc;
    bf16x8 v0 = *(const bf16x8*)(src);
    bf16x8 v1 = *(const bf16x8*)(src + 8);
#pragma unroll
    for (int i = 0; i < 8; ++i) { t[sl][cc + i] = v0[i]; t[sl][cc + 8 + i] = v1[i]; }
    __syncthreads();
    const int hl = tt >> 2;
    bf16* dst = vt + ((long long)z * 192 + hd0 + hl) * 512 + s0 + cc;
    bf16x8 o0, o1;
#pragma unroll
    for (int i = 0; i < 8; ++i) { o0[i] = t[cc + i][hl]; o1[i] = t[cc + 8 + i][hl]; }
    *(bf16x8*)dst = o0;
    *(bf16x8*)(dst + 8) = o1;
}

// in-place row softmax over 512 bf16; one wave per row
__global__ __launch_bounds__(256)
void softmax_kernel(bf16* __restrict__ S)
{
    const int row  = blockIdx.x * 4 + (threadIdx.x >> 6);
    const int lane = threadIdx.x & 63;
    bf16* p = S + (long long)row * 512 + lane * 8;
    bf16x8 v8 = *(bf16x8*)p;
    float v[8];
#pragma unroll
    for (int i = 0; i < 8; ++i) v[i] = (float)v8[i];
    float m = v[0];
#pragma unroll
    for (int i = 1; i < 8; ++i) m = fmaxf(m, v[i]);
    for (int off = 32; off; off >>= 1) m = fmaxf(m, __shfl_xor(m, off));
    float sum = 0.f;
#pragma unroll
    for (int i = 0; i < 8; ++i) { v[i] = __expf(v[i] - m); sum += v[i]; }
    for (int off = 32; off; off >>= 1) sum += __shfl_xor(sum, off);
    const float r = 1.0f / sum;
    bf16x8 o;
#pragma unroll
    for (int i = 0; i < 8; ++i) o[i] = (bf16)(v[i] * r);
    *(bf16x8*)p = o;
}

// LayerNorm(a_row + b_row) * g + beta -> o   (768 cols, 3 per thread)
// NOTE: no __restrict__ — LN2 runs in-place (b == o).
__global__ __launch_bounds__(256)
void ln_kernel(const bf16* a, int lda_, const bf16* b, int ldb_,
               bf16* o, int ldo, const float* g, const float* be)
{
    const int row = blockIdx.x;
    const int t   = threadIdx.x;
    const bf16* pa = a + (long long)row * lda_;
    const bf16* pb = b + (long long)row * ldb_;
    float xv[3];
#pragma unroll
    for (int k = 0; k < 3; ++k) {
        const int d = t + k * 256;
        xv[k] = (float)pa[d] + (float)pb[d];
    }
    float s1 = xv[0] + xv[1] + xv[2];
    float s2 = xv[0]*xv[0] + xv[1]*xv[1] + xv[2]*xv[2];
    for (int off = 32; off; off >>= 1) {
        s1 += __shfl_xor(s1, off);
        s2 += __shfl_xor(s2, off);
    }
    __shared__ float red[8];
    const int wid = t >> 6, lane = t & 63;
    if (lane == 0) { red[wid] = s1; red[4 + wid] = s2; }
    __syncthreads();
    s1 = red[0] + red[1] + red[2] + red[3];
    s2 = red[4] + red[5] + red[6] + red[7];
    const float mu  = s1 * (1.0f / 768.0f);
    const float var = s2 * (1.0f / 768.0f) - mu * mu;
    const float rs  = rsqrtf(var + 1e-5f);
    bf16* po = o + (long long)row * ldo;
#pragma unroll
    for (int k = 0; k < 3; ++k) {
        const int d = t + k * 256;
        po[d] = (bf16)(((xv[k] - mu) * rs) * g[d] + be[d]);
    }
}

// fused bias, coalesced: 32 lanes per output row.
// blocks 0..287: bcat[n] = inpb[n] + dot(inpw[n,:], b_src); blocks 288+: bx copy
__global__ __launch_bounds__(256)
void make_bias_kernel(const float* __restrict__ inpw, const float* __restrict__ inpb,
                      const float* __restrict__ bq, const float* __restrict__ bk,
                      const float* __restrict__ bv, const float* __restrict__ bx,
                      float* __restrict__ bcat)
{
    const int blk = blockIdx.x;
    if (blk < 288) {
        const int g = threadIdx.x >> 5, l = threadIdx.x & 31;
        const int n = blk * 8 + g;                  // 0..2303
        const int zsec = n / 768;
        const float* bb = (zsec == 0) ? bq : ((zsec == 1) ? bk : bv);
        const float* wrow = inpw + (long long)n * 768;
        float s = 0.f;
        for (int d = l; d < 768; d += 32) s += wrow[d] * bb[d];
#pragma unroll
        for (int off = 16; off; off >>= 1) s += __shfl_xor(s, off);
        if (l == 0) bcat[n] = inpb[n] + s;
    } else {
        const int n = (blk - 288) * 256 + threadIdx.x;
        if (n < 768) bcat[2304 + n] = bx[n];
    }
}

// stage 1: partial[b][c][d] = sum over 32 rows of x2[b, c*32+r, d]
__global__ __launch_bounds__(256)
void reduce_stage1_kernel(const bf16* __restrict__ x2, float* __restrict__ partial)
{
    const int b = blockIdx.x, c = blockIdx.y, t = threadIdx.x;
    const bf16* base = x2 + (long long)(b * 512 + c * 32) * 3072;
    float a0 = 0.f, a1 = 0.f, a2 = 0.f;
    for (int s = 0; s < 32; ++s) {
        const bf16* row = base + (long long)s * 3072;
        a0 += (float)row[t];
        a1 += (float)row[t + 256];
        a2 += (float)row[t + 512];
    }
    float* p = partial + (long long)(b * 16 + c) * 768;
    p[t] = a0; p[t + 256] = a1; p[t + 512] = a2;
}

// stage 2: red[d] = sum_c partial; out[b,:] = red @ w^T + bias
__global__ __launch_bounds__(256)
void reduce_fc2_stage2_kernel(const float* __restrict__ partial, const float* __restrict__ w,
                              const float* __restrict__ bias, float* __restrict__ out)
{
    const int b = blockIdx.x, t = threadIdx.x;
    float a0 = 0.f, a1 = 0.f, a2 = 0.f;
    for (int c = 0; c < 16; ++c) {
        const float* p = partial + (long long)(b * 16 + c) * 768;
        a0 += p[t]; a1 += p[t + 256]; a2 += p[t + 512];
    }
    __shared__ float os[10];
    if (t < 10) os[t] = 0.f;
    __syncthreads();
    for (int c = 0; c < 10; ++c) {
        float p = w[c * 768 + t] * a0 + w[c * 768 + t + 256] * a1 + w[c * 768 + t + 512] * a2;
        for (int off = 32; off; off >>= 1) p += __shfl_xor(p, off);
        if ((t & 63) == 0) atomicAdd(&os[c], p);
    }
    __syncthreads();
    if (t < 10) out[b * 10 + t] = os[t] + bias[t];
}

// ---------------------------------------------------------------------------
// workspace layout (bytes)
// ---------------------------------------------------------------------------
static const size_t OFF_XPE  = 0;
static const size_t OFF_WCAT = OFF_XPE  + (size_t)16384 * 768 * 2;
static const size_t OFF_WT3  = OFF_WCAT + (size_t)3072 * 768 * 2;
static const size_t OFF_INPJ = OFF_WT3  + (size_t)3 * 768 * 768 * 2;
static const size_t OFF_WOUT = OFF_INPJ + (size_t)2304 * 768 * 2;
static const size_t OFF_WF1A = OFF_WOUT + (size_t)768 * 768 * 2;
static const size_t OFF_WF1B = OFF_WF1A + (size_t)768 * 768 * 2;
static const size_t OFF_BCAT = OFF_WF1B + (size_t)768 * 768 * 2;
static const size_t OFF_QKVX = OFF_BCAT + (size_t)3072 * 4;
static const size_t OFF_VT   = OFF_QKVX + (size_t)16384 * 3072 * 2;
static const size_t OFF_S    = OFF_VT   + (size_t)128 * 192 * 512 * 2;   // also: PE table / fc2 partials
static const size_t OFF_X1   = OFF_S    + (size_t)128 * 512 * 512 * 2;
// total = OFF_X1 + 16384*768*2 = 258,617,344 bytes

extern "C" void kernel_launch(void* const* d_in, const int* in_sizes, int n_in,
                              void* d_out, int out_size, void* d_ws, size_t ws_size,
                              hipStream_t stream)
{
    const float* x     = (const float*)d_in[0];
    const float* wq    = (const float*)d_in[1];
    const float* bq    = (const float*)d_in[2];
    const float* wk    = (const float*)d_in[3];
    const float* bk    = (const float*)d_in[4];
    const float* wv    = (const float*)d_in[5];
    const float* bv    = (const float*)d_in[6];
    const float* wx    = (const float*)d_in[7];
    const float* bx    = (const float*)d_in[8];
    const float* inpw  = (const float*)d_in[9];
    const float* inpb  = (const float*)d_in[10];
    const float* woutp = (const float*)d_in[11];
    const float* boutp = (const float*)d_in[12];
    const float* wf1a  = (const float*)d_in[13];
    const float* bf1a  = (const float*)d_in[14];
    const float* wf1b  = (const float*)d_in[15];
    const float* bf1b  = (const float*)d_in[16];
    const float* lng   = (const float*)d_in[17];
    const float* lnb   = (const float*)d_in[18];
    const float* wfc2  = (const float*)d_in[19];
    const float* bfc2  = (const float*)d_in[20];
    float* out = (float*)d_out;

    char* ws = (char*)d_ws;
    bf16*  XPE  = (bf16*)(ws + OFF_XPE);
    bf16*  WCAT = (bf16*)(ws + OFF_WCAT);
    bf16*  WT3  = (bf16*)(ws + OFF_WT3);
    bf16*  INPJ = (bf16*)(ws + OFF_INPJ);
    bf16*  WOUT = (bf16*)(ws + OFF_WOUT);
    bf16*  WF1A = (bf16*)(ws + OFF_WF1A);
    bf16*  WF1B = (bf16*)(ws + OFF_WF1B);
    float* BCAT = (float*)(ws + OFF_BCAT);
    bf16*  QKVX = (bf16*)(ws + OFF_QKVX);
    bf16*  VT   = (bf16*)(ws + OFF_VT);
    bf16*  Smat = (bf16*)(ws + OFF_S);
    float* PET  = (float*)(ws + OFF_S);    // PE table, consumed before Smat written
    float* PART = (float*)(ws + OFF_S);    // fc2 partials, after Smat dead
    bf16*  X1   = (bf16*)(ws + OFF_X1);

    // ---- weight prep ----
    cast_t_kernel<<<dim3(24, 24), 256, 0, stream>>>(wq, WT3);
    cast_t_kernel<<<dim3(24, 24), 256, 0, stream>>>(wk, WT3 + 589824);
    cast_t_kernel<<<dim3(24, 24), 256, 0, stream>>>(wv, WT3 + 2 * 589824);
    cast_kernel<<<1728, 256, 0, stream>>>(inpw, INPJ, 442368);
    cast_kernel<<<576, 256, 0, stream>>>(woutp, WOUT, 147456);
    cast_kernel<<<576, 256, 0, stream>>>(wf1a, WF1A, 147456);
    cast_kernel<<<576, 256, 0, stream>>>(wf1b, WF1B, 147456);
    cast_kernel<<<576, 256, 0, stream>>>(wx, WCAT + (size_t)2304 * 768, 147456);
    // W_eff[z] = in_proj_w[z] @ w{q,k,v}  (batched, NT with transposed first-layer weights)
    gemm_nt<128, 128, 4, 4><<<dim3(6, 6, 3), 256, 0, stream>>>(
        INPJ, WT3, WCAT, nullptr, 768, 768, 768, 768,
        1, 589824, 0, 589824, 0, 589824, 0, 1.0f, 0);
    make_bias_kernel<<<291, 256, 0, stream>>>(inpw, inpb, bq, bk, bv, bx, BCAT);

    // ---- activations ----
    pe_table_kernel<<<384, 256, 0, stream>>>(PET);
    pe_cast_kernel<<<12288, 256, 0, stream>>>(x, PET, XPE);

    // QKVX = XPE @ WCAT^T + BCAT   -> [16384, 3072] = Q2|K2|V2|XR
    gemm_nt<128, 128, 4, 4><<<dim3(24, 128, 1), 256, 0, stream>>>(
        XPE, WCAT, QKVX, BCAT, 768, 768, 768, 3072,
        1, 0, 0, 0, 0, 0, 0, 1.0f, 0);

    transpose_v_kernel<<<dim3(3, 8, 128), 256, 0, stream>>>(QKVX, VT);

    // scores = Q2 K2^T / sqrt(192), batched over (b,h)
    gemm_nt<128, 128, 4, 4><<<dim3(4, 4, 128), 256, 0, stream>>>(
        QKVX, QKVX + 768, Smat, nullptr, 192, 3072, 3072, 512,
        4, 1572864, 192, 1572864, 192, 1048576, 262144, 0.0721687836f, 0);

    softmax_kernel<<<16384, 256, 0, stream>>>(Smat);

    // ctx = P @ V  (VT is [hd, s] so this is NT), writes into Q2 region
    gemm_nt<128, 64, 4, 2><<<dim3(3, 4, 128), 256, 0, stream>>>(
        Smat, VT, QKVX, nullptr, 512, 512, 512, 3072,
        4, 1048576, 262144, 393216, 98304, 1572864, 192, 1.0f, 0);

    // attn_out = ctx @ out_proj^T + b, writes into K2 region
    gemm_nt<128, 128, 4, 4><<<dim3(6, 128, 1), 256, 0, stream>>>(
        QKVX, WOUT, QKVX + 768, boutp, 768, 3072, 768, 3072,
        1, 0, 0, 0, 0, 0, 0, 1.0f, 0);

    // x1 = LN(XR + attn_out)
    ln_kernel<<<16384, 256, 0, stream>>>(QKVX + 2304, 3072, QKVX + 768, 3072,
                                         X1, 768, lng, lnb);

    // h1 = relu(x1 @ fc1a^T + b) -> V2 region
    gemm_nt<128, 128, 4, 4><<<dim3(6, 128, 1), 256, 0, stream>>>(
        X1, WF1A, QKVX + 1536, bf1a, 768, 768, 768, 3072,
        1, 0, 0, 0, 0, 0, 0, 1.0f, 1);

    // ffn = h1 @ fc1b^T + b -> XR region
    gemm_nt<128, 128, 4, 4><<<dim3(6, 128, 1), 256, 0, stream>>>(
        QKVX + 1536, WF1B, QKVX + 2304, bf1b, 768, 3072, 768, 3072,
        1, 0, 0, 0, 0, 0, 0, 1.0f, 0);

    // x2 = LN(x1 + ffn), in-place over ffn region
    ln_kernel<<<16384, 256, 0, stream>>>(X1, 768, QKVX + 2304, 3072,
                                         QKVX + 2304, 3072, lng, lnb);

    // out = (sum_s x2) @ fc2^T + b
    reduce_stage1_kernel<<<dim3(32, 16), 256, 0, stream>>>(QKVX + 2304, PART);
    reduce_fc2_stage2_kernel<<<32, 256, 0, stream>>>(PART, wfc2, bfc2, out);
}

// Round 3
// 550.999 us; speedup vs baseline: 1.2128x; 1.1397x over previous
//
#include <hip/hip_runtime.h>
#include <hip/hip_bf16.h>

typedef __bf16 bf16;
typedef __bf16 bf16x8 __attribute__((ext_vector_type(8)));
typedef __bf16 bf16x4 __attribute__((ext_vector_type(4)));
typedef float  f32x4  __attribute__((ext_vector_type(4)));

#define GLD16(g, l) __builtin_amdgcn_global_load_lds(                        \
    (const __attribute__((address_space(1))) void*)(g),                      \
    (__attribute__((address_space(3))) void*)(l), 16, 0, 0)

// ---------------------------------------------------------------------------
// NT GEMM: C[m,n] = alpha * sum_k A[m,k]*B[n,k] (+ bias[n]) (+ relu)
// BK=64 (2 barriers per 32 MFMA, vs per 16 at BK=32 — latency-bound regime).
// LDS swizzle for 128-B rows: phys 16B chunk p at row r holds global chunk
// p ^ (r&7).  Staging lane (8 lanes/row) fetches global chunk
// (lane&7)^(lane>>3) — pure lane function, GLD16-compatible.  Fragment
// reads: slot = q ^ (lr&7) -> 2 lanes per 4-bank slot = conflict-free (m136).
// Staging pointers are bumped (+64 elems/iter), not recomputed.
// ---------------------------------------------------------------------------
template<int BM, int BN, int MFR, int NFR>
__global__ __launch_bounds__(256, 3)
void gemm_nt(const bf16* __restrict__ A, const bf16* __restrict__ B,
             bf16* __restrict__ C, const float* __restrict__ bias,
             int K, int lda, int ldb, int ldc,
             int inner,
             long long aOut, long long aIn,
             long long bOut, long long bIn,
             long long cOut, long long cIn,
             float alpha, int relu)
{
    const int z  = blockIdx.z;
    const int zo = z / inner;
    const int zi = z - zo * inner;
    A += (long long)zo * aOut + (long long)zi * aIn;
    B += (long long)zo * bOut + (long long)zi * bIn;
    C += (long long)zo * cOut + (long long)zi * cIn;

    const int tm = blockIdx.y * BM;
    const int tn = blockIdx.x * BN;

    __shared__ __align__(16) bf16 smem[(BM + BN) * 64];
    bf16* As = smem;
    bf16* Bs = smem + BM * 64;

    const int tid  = threadIdx.x;
    const int lane = tid & 63;
    const int wid  = tid >> 6;
    const int wr   = wid >> 1;   // wave row (2)
    const int wc   = wid & 1;    // wave col (2)

    f32x4 acc[MFR][NFR];
#pragma unroll
    for (int i = 0; i < MFR; ++i)
#pragma unroll
        for (int j = 0; j < NFR; ++j) acc[i][j] = (f32x4){0.f, 0.f, 0.f, 0.f};

    // staging lane map: 8 lanes/row, swizzled global 16B-chunk
    const int srow = lane >> 3;                  // row within 8-row group
    const int gch8 = ((lane & 7) ^ srow) * 8;    // global k elem offset fetched

    const int NA = BM / 32;      // A GLD16s per wave
    const int NB = BN / 32;      // B GLD16s per wave

    const bf16* aP[NA];
#pragma unroll
    for (int jj = 0; jj < NA; ++jj) {
        const int R0 = (wid * NA + jj) * 8;
        aP[jj] = A + (long long)(tm + R0 + srow) * lda + gch8;
    }
    const bf16* bP[NB];
#pragma unroll
    for (int jj = 0; jj < NB; ++jj) {
        const int R0 = (wid * NB + jj) * 8;
        bP[jj] = B + (long long)(tn + R0 + srow) * ldb + gch8;
    }

    const int lr = lane & 15;    // mfma row/col within 16
    const int qg = lane >> 4;    // k-chunk group 0..3

    for (int kt = 0; kt < K; kt += 64) {
#pragma unroll
        for (int jj = 0; jj < NA; ++jj)
            GLD16(aP[jj], As + (wid * NA + jj) * 512);
#pragma unroll
        for (int jj = 0; jj < NB; ++jj)
            GLD16(bP[jj], Bs + (wid * NB + jj) * 512);
        __syncthreads();   // drains vmcnt (global_load_lds) + barrier

#pragma unroll
        for (int h = 0; h < 2; ++h) {
            const int off = ((qg + h * 4) ^ (lr & 7)) * 8;   // swizzled phys chunk
            bf16x8 af[MFR], bfr[NFR];
#pragma unroll
            for (int i = 0; i < MFR; ++i)
                af[i] = *(const bf16x8*)(As + (wr * MFR * 16 + i * 16 + lr) * 64 + off);
#pragma unroll
            for (int j = 0; j < NFR; ++j)
                bfr[j] = *(const bf16x8*)(Bs + (wc * NFR * 16 + j * 16 + lr) * 64 + off);
#pragma unroll
            for (int i = 0; i < MFR; ++i)
#pragma unroll
                for (int j = 0; j < NFR; ++j)
                    acc[i][j] = __builtin_amdgcn_mfma_f32_16x16x32_bf16(
                        af[i], bfr[j], acc[i][j], 0, 0, 0);
        }
        __syncthreads();
#pragma unroll
        for (int jj = 0; jj < NA; ++jj) aP[jj] += 64;
#pragma unroll
        for (int jj = 0; jj < NB; ++jj) bP[jj] += 64;
    }

    // epilogue: C/D layout col=lane&15, row=(lane>>4)*4+reg  [m89-verified]
#pragma unroll
    for (int i = 0; i < MFR; ++i) {
#pragma unroll
        for (int j = 0; j < NFR; ++j) {
#pragma unroll
            for (int r = 0; r < 4; ++r) {
                const int mm = tm + wr * MFR * 16 + i * 16 + (lane >> 4) * 4 + r;
                const int nn = tn + wc * NFR * 16 + j * 16 + (lane & 15);
                float v = acc[i][j][r] * alpha;
                if (bias) v += bias[nn];
                if (relu) v = fmaxf(v, 0.f);
                C[(long long)mm * ldc + nn] = (bf16)v;
            }
        }
    }
}

// ---------------------------------------------------------------------------
// PE table [512][768] fp32 (computed once, L2/L3-resident for the add pass)
// ---------------------------------------------------------------------------
__global__ __launch_bounds__(256)
void pe_table_kernel(float* __restrict__ pe)
{
    const int idx4 = (blockIdx.x * 256 + threadIdx.x) * 4;   // over 512*768
    const int d    = idx4 % 768;
    const int s    = idx4 / 768;
    const float ksc = -0.034603417655076f;  // -2*log2(10000)/768
    float a0 = (float)s * exp2f((float)d * ksc);
    float a1 = (float)s * exp2f((float)(d + 2) * ksc);
    float s0, c0, s1, c1;
    sincosf(a0, &s0, &c0);
    sincosf(a1, &s1, &c1);
    *(float4*)(pe + idx4) = make_float4(s0, c0, s1, c1);
}

// x + PE, fp32 -> bf16.  [16384,768]; one thread per 4 elems.
__global__ __launch_bounds__(256)
void pe_cast_kernel(const float* __restrict__ x, const float* __restrict__ pe,
                    bf16* __restrict__ out)
{
    const int idx4 = (blockIdx.x * 256 + threadIdx.x) * 4;
    const int d    = idx4 % 768;
    const int row  = idx4 / 768;
    const int s    = row & 511;
    const float4 xv = *(const float4*)(x + (long long)idx4);
    const float4 pv = *(const float4*)(pe + s * 768 + d);
    bf16x4 o;
    o[0] = (bf16)(xv.x + pv.x);
    o[1] = (bf16)(xv.y + pv.y);
    o[2] = (bf16)(xv.z + pv.z);
    o[3] = (bf16)(xv.w + pv.w);
    *(bf16x4*)(out + (long long)idx4) = o;
}

// flat fp32 -> bf16 cast, 4 elems/thread
__global__ __launch_bounds__(256)
void cast_kernel(const float* __restrict__ src, bf16* __restrict__ dst, int n4)
{
    const int i = blockIdx.x * 256 + threadIdx.x;
    if (i < n4) {
        const float4 v = *(const float4*)(src + (long long)i * 4);
        bf16x4 o;
        o[0] = (bf16)v.x; o[1] = (bf16)v.y; o[2] = (bf16)v.z; o[3] = (bf16)v.w;
        *(bf16x4*)(dst + (long long)i * 4) = o;
    }
}

// 768x768 transpose + cast: dst[c][r] = src[r][c]
__global__ __launch_bounds__(256)
void cast_t_kernel(const float* __restrict__ src, bf16* __restrict__ dst)
{
    __shared__ bf16 t[32][33];
    const int r0 = blockIdx.y * 32, c0 = blockIdx.x * 32;
    const int tr = threadIdx.x >> 5, tc = threadIdx.x & 31;
#pragma unroll
    for (int k = 0; k < 4; ++k) {
        const int r = tr + k * 8;
        t[r][tc] = (bf16)src[(long long)(r0 + r) * 768 + c0 + tc];
    }
    __syncthreads();
#pragma unroll
    for (int k = 0; k < 4; ++k) {
        const int c = tr + k * 8;
        dst[(long long)(c0 + c) * 768 + r0 + tc] = t[tc][c];
    }
}

// V2 [16384, cols 1536..2304 of 3072] -> VT [128][192][512]
__global__ __launch_bounds__(256)
void transpose_v_kernel(const bf16* __restrict__ qkvx, bf16* __restrict__ vt)
{
    __shared__ __align__(16) bf16 t[64][80];
    const int z  = blockIdx.z;          // b*4+h
    const int b  = z >> 2, h = z & 3;
    const int s0 = blockIdx.y * 64;
    const int hd0 = blockIdx.x * 64;
    const int tt = threadIdx.x;
    const int sl = tt >> 2;
    const int cc = (tt & 3) * 16;
    const bf16* src = qkvx + (long long)(b * 512 + s0 + sl) * 3072 + 1536 + h * 192 + hd0 + cc;
    bf16x8 v0 = *(const bf16x8*)(src);
    bf16x8 v1 = *(const bf16x8*)(src + 8);
#pragma unroll
    for (int i = 0; i < 8; ++i) { t[sl][cc + i] = v0[i]; t[sl][cc + 8 + i] = v1[i]; }
    __syncthreads();
    const int hl = tt >> 2;
    bf16* dst = vt + ((long long)z * 192 + hd0 + hl) * 512 + s0 + cc;
    bf16x8 o0, o1;
#pragma unroll
    for (int i = 0; i < 8; ++i) { o0[i] = t[cc + i][hl]; o1[i] = t[cc + 8 + i][hl]; }
    *(bf16x8*)dst = o0;
    *(bf16x8*)(dst + 8) = o1;
}

// in-place row softmax over 512 bf16; one wave per row
__global__ __launch_bounds__(256)
void softmax_kernel(bf16* __restrict__ S)
{
    const int row  = blockIdx.x * 4 + (threadIdx.x >> 6);
    const int lane = threadIdx.x & 63;
    bf16* p = S + (long long)row * 512 + lane * 8;
    bf16x8 v8 = *(bf16x8*)p;
    float v[8];
#pragma unroll
    for (int i = 0; i < 8; ++i) v[i] = (float)v8[i];
    float m = v[0];
#pragma unroll
    for (int i = 1; i < 8; ++i) m = fmaxf(m, v[i]);
    for (int off = 32; off; off >>= 1) m = fmaxf(m, __shfl_xor(m, off));
    float sum = 0.f;
#pragma unroll
    for (int i = 0; i < 8; ++i) { v[i] = __expf(v[i] - m); sum += v[i]; }
    for (int off = 32; off; off >>= 1) sum += __shfl_xor(sum, off);
    const float r = 1.0f / sum;
    bf16x8 o;
#pragma unroll
    for (int i = 0; i < 8; ++i) o[i] = (bf16)(v[i] * r);
    *(bf16x8*)p = o;
}

// LayerNorm(a_row + b_row) * g + beta -> o   (768 cols, 4/thread, bf16x4)
// NOTE: no __restrict__ — LN2 runs in-place (b == o).  192 threads.
__global__ __launch_bounds__(192)
void ln_kernel(const bf16* a, int lda_, const bf16* b, int ldb_,
               bf16* o, int ldo, const float* g, const float* be)
{
    const int row = blockIdx.x;
    const int t   = threadIdx.x;       // 0..191
    const int d0  = t * 4;
    const bf16x4 av = *(const bf16x4*)(a + (long long)row * lda_ + d0);
    const bf16x4 bv = *(const bf16x4*)(b + (long long)row * ldb_ + d0);
    float xv[4];
#pragma unroll
    for (int k = 0; k < 4; ++k) xv[k] = (float)av[k] + (float)bv[k];
    float s1 = xv[0] + xv[1] + xv[2] + xv[3];
    float s2 = xv[0]*xv[0] + xv[1]*xv[1] + xv[2]*xv[2] + xv[3]*xv[3];
    for (int off = 32; off; off >>= 1) {
        s1 += __shfl_xor(s1, off);
        s2 += __shfl_xor(s2, off);
    }
    __shared__ float red[6];
    const int wid = t >> 6, lane = t & 63;
    if (lane == 0) { red[wid] = s1; red[3 + wid] = s2; }
    __syncthreads();
    s1 = red[0] + red[1] + red[2];
    s2 = red[3] + red[4] + red[5];
    const float mu  = s1 * (1.0f / 768.0f);
    const float var = s2 * (1.0f / 768.0f) - mu * mu;
    const float rs  = rsqrtf(var + 1e-5f);
    const float4 gv = *(const float4*)(g + d0);
    const float4 ev = *(const float4*)(be + d0);
    bf16x4 ov;
    ov[0] = (bf16)(((xv[0] - mu) * rs) * gv.x + ev.x);
    ov[1] = (bf16)(((xv[1] - mu) * rs) * gv.y + ev.y);
    ov[2] = (bf16)(((xv[2] - mu) * rs) * gv.z + ev.z);
    ov[3] = (bf16)(((xv[3] - mu) * rs) * gv.w + ev.w);
    *(bf16x4*)(o + (long long)row * ldo + d0) = ov;
}

// fused bias, coalesced: 32 lanes per output row.
// blocks 0..287: bcat[n] = inpb[n] + dot(inpw[n,:], b_src); blocks 288+: bx copy
__global__ __launch_bounds__(256)
void make_bias_kernel(const float* __restrict__ inpw, const float* __restrict__ inpb,
                      const float* __restrict__ bq, const float* __restrict__ bk,
                      const float* __restrict__ bv, const float* __restrict__ bx,
                      float* __restrict__ bcat)
{
    const int blk = blockIdx.x;
    if (blk < 288) {
        const int g = threadIdx.x >> 5, l = threadIdx.x & 31;
        const int n = blk * 8 + g;                  // 0..2303
        const int zsec = n / 768;
        const float* bb = (zsec == 0) ? bq : ((zsec == 1) ? bk : bv);
        const float* wrow = inpw + (long long)n * 768;
        float s = 0.f;
        for (int d = l; d < 768; d += 32) s += wrow[d] * bb[d];
#pragma unroll
        for (int off = 16; off; off >>= 1) s += __shfl_xor(s, off);
        if (l == 0) bcat[n] = inpb[n] + s;
    } else {
        const int n = (blk - 288) * 256 + threadIdx.x;
        if (n < 768) bcat[2304 + n] = bx[n];
    }
}

// stage 1: partial[b][c][d] = sum over 32 rows of x2[b, c*32+r, d]
__global__ __launch_bounds__(256)
void reduce_stage1_kernel(const bf16* __restrict__ x2, float* __restrict__ partial)
{
    const int b = blockIdx.x, c = blockIdx.y, t = threadIdx.x;
    const bf16* base = x2 + (long long)(b * 512 + c * 32) * 3072;
    float a0 = 0.f, a1 = 0.f, a2 = 0.f;
    for (int s = 0; s < 32; ++s) {
        const bf16* row = base + (long long)s * 3072;
        a0 += (float)row[t];
        a1 += (float)row[t + 256];
        a2 += (float)row[t + 512];
    }
    float* p = partial + (long long)(b * 16 + c) * 768;
    p[t] = a0; p[t + 256] = a1; p[t + 512] = a2;
}

// stage 2: red[d] = sum_c partial; out[b,:] = red @ w^T + bias
__global__ __launch_bounds__(256)
void reduce_fc2_stage2_kernel(const float* __restrict__ partial, const float* __restrict__ w,
                              const float* __restrict__ bias, float* __restrict__ out)
{
    const int b = blockIdx.x, t = threadIdx.x;
    float a0 = 0.f, a1 = 0.f, a2 = 0.f;
    for (int c = 0; c < 16; ++c) {
        const float* p = partial + (long long)(b * 16 + c) * 768;
        a0 += p[t]; a1 += p[t + 256]; a2 += p[t + 512];
    }
    __shared__ float os[10];
    if (t < 10) os[t] = 0.f;
    __syncthreads();
    for (int c = 0; c < 10; ++c) {
        float p = w[c * 768 + t] * a0 + w[c * 768 + t + 256] * a1 + w[c * 768 + t + 512] * a2;
        for (int off = 32; off; off >>= 1) p += __shfl_xor(p, off);
        if ((t & 63) == 0) atomicAdd(&os[c], p);
    }
    __syncthreads();
    if (t < 10) out[b * 10 + t] = os[t] + bias[t];
}

// ---------------------------------------------------------------------------
// workspace layout (bytes)
// ---------------------------------------------------------------------------
static const size_t OFF_XPE  = 0;
static const size_t OFF_WCAT = OFF_XPE  + (size_t)16384 * 768 * 2;
static const size_t OFF_WT3  = OFF_WCAT + (size_t)3072 * 768 * 2;
static const size_t OFF_INPJ = OFF_WT3  + (size_t)3 * 768 * 768 * 2;
static const size_t OFF_WOUT = OFF_INPJ + (size_t)2304 * 768 * 2;
static const size_t OFF_WF1A = OFF_WOUT + (size_t)768 * 768 * 2;
static const size_t OFF_WF1B = OFF_WF1A + (size_t)768 * 768 * 2;
static const size_t OFF_BCAT = OFF_WF1B + (size_t)768 * 768 * 2;
static const size_t OFF_QKVX = OFF_BCAT + (size_t)3072 * 4;
static const size_t OFF_VT   = OFF_QKVX + (size_t)16384 * 3072 * 2;
static const size_t OFF_S    = OFF_VT   + (size_t)128 * 192 * 512 * 2;   // also: PE table / fc2 partials
static const size_t OFF_X1   = OFF_S    + (size_t)128 * 512 * 512 * 2;
// total = OFF_X1 + 16384*768*2 = 258,617,344 bytes

extern "C" void kernel_launch(void* const* d_in, const int* in_sizes, int n_in,
                              void* d_out, int out_size, void* d_ws, size_t ws_size,
                              hipStream_t stream)
{
    const float* x     = (const float*)d_in[0];
    const float* wq    = (const float*)d_in[1];
    const float* bq    = (const float*)d_in[2];
    const float* wk    = (const float*)d_in[3];
    const float* bk    = (const float*)d_in[4];
    const float* wv    = (const float*)d_in[5];
    const float* bv    = (const float*)d_in[6];
    const float* wx    = (const float*)d_in[7];
    const float* bx    = (const float*)d_in[8];
    const float* inpw  = (const float*)d_in[9];
    const float* inpb  = (const float*)d_in[10];
    const float* woutp = (const float*)d_in[11];
    const float* boutp = (const float*)d_in[12];
    const float* wf1a  = (const float*)d_in[13];
    const float* bf1a  = (const float*)d_in[14];
    const float* wf1b  = (const float*)d_in[15];
    const float* bf1b  = (const float*)d_in[16];
    const float* lng   = (const float*)d_in[17];
    const float* lnb   = (const float*)d_in[18];
    const float* wfc2  = (const float*)d_in[19];
    const float* bfc2  = (const float*)d_in[20];
    float* out = (float*)d_out;

    char* ws = (char*)d_ws;
    bf16*  XPE  = (bf16*)(ws + OFF_XPE);
    bf16*  WCAT = (bf16*)(ws + OFF_WCAT);
    bf16*  WT3  = (bf16*)(ws + OFF_WT3);
    bf16*  INPJ = (bf16*)(ws + OFF_INPJ);
    bf16*  WOUT = (bf16*)(ws + OFF_WOUT);
    bf16*  WF1A = (bf16*)(ws + OFF_WF1A);
    bf16*  WF1B = (bf16*)(ws + OFF_WF1B);
    float* BCAT = (float*)(ws + OFF_BCAT);
    bf16*  QKVX = (bf16*)(ws + OFF_QKVX);
    bf16*  VT   = (bf16*)(ws + OFF_VT);
    bf16*  Smat = (bf16*)(ws + OFF_S);
    float* PET  = (float*)(ws + OFF_S);    // PE table, consumed before Smat written
    float* PART = (float*)(ws + OFF_S);    // fc2 partials, after Smat dead
    bf16*  X1   = (bf16*)(ws + OFF_X1);

    // ---- weight prep ----
    cast_t_kernel<<<dim3(24, 24), 256, 0, stream>>>(wq, WT3);
    cast_t_kernel<<<dim3(24, 24), 256, 0, stream>>>(wk, WT3 + 589824);
    cast_t_kernel<<<dim3(24, 24), 256, 0, stream>>>(wv, WT3 + 2 * 589824);
    cast_kernel<<<1728, 256, 0, stream>>>(inpw, INPJ, 442368);
    cast_kernel<<<576, 256, 0, stream>>>(woutp, WOUT, 147456);
    cast_kernel<<<576, 256, 0, stream>>>(wf1a, WF1A, 147456);
    cast_kernel<<<576, 256, 0, stream>>>(wf1b, WF1B, 147456);
    cast_kernel<<<576, 256, 0, stream>>>(wx, WCAT + (size_t)2304 * 768, 147456);
    // W_eff[z] = in_proj_w[z] @ w{q,k,v}  (batched, NT with transposed first-layer weights)
    gemm_nt<128, 128, 4, 4><<<dim3(6, 6, 3), 256, 0, stream>>>(
        INPJ, WT3, WCAT, nullptr, 768, 768, 768, 768,
        1, 589824, 0, 589824, 0, 589824, 0, 1.0f, 0);
    make_bias_kernel<<<291, 256, 0, stream>>>(inpw, inpb, bq, bk, bv, bx, BCAT);

    // ---- activations ----
    pe_table_kernel<<<384, 256, 0, stream>>>(PET);
    pe_cast_kernel<<<12288, 256, 0, stream>>>(x, PET, XPE);

    // QKVX = XPE @ WCAT^T + BCAT   -> [16384, 3072] = Q2|K2|V2|XR
    gemm_nt<128, 128, 4, 4><<<dim3(24, 128, 1), 256, 0, stream>>>(
        XPE, WCAT, QKVX, BCAT, 768, 768, 768, 3072,
        1, 0, 0, 0, 0, 0, 0, 1.0f, 0);

    transpose_v_kernel<<<dim3(3, 8, 128), 256, 0, stream>>>(QKVX, VT);

    // scores = Q2 K2^T / sqrt(192), batched over (b,h)
    gemm_nt<128, 128, 4, 4><<<dim3(4, 4, 128), 256, 0, stream>>>(
        QKVX, QKVX + 768, Smat, nullptr, 192, 3072, 3072, 512,
        4, 1572864, 192, 1572864, 192, 1048576, 262144, 0.0721687836f, 0);

    softmax_kernel<<<16384, 256, 0, stream>>>(Smat);

    // ctx = P @ V  (VT is [hd, s] so this is NT), writes into Q2 region
    gemm_nt<128, 64, 4, 2><<<dim3(3, 4, 128), 256, 0, stream>>>(
        Smat, VT, QKVX, nullptr, 512, 512, 512, 3072,
        4, 1048576, 262144, 393216, 98304, 1572864, 192, 1.0f, 0);

    // attn_out = ctx @ out_proj^T + b, writes into K2 region
    gemm_nt<128, 128, 4, 4><<<dim3(6, 128, 1), 256, 0, stream>>>(
        QKVX, WOUT, QKVX + 768, boutp, 768, 3072, 768, 3072,
        1, 0, 0, 0, 0, 0, 0, 1.0f, 0);

    // x1 = LN(XR + attn_out)
    ln_kernel<<<16384, 192, 0, stream>>>(QKVX + 2304, 3072, QKVX + 768, 3072,
                                         X1, 768, lng, lnb);

    // h1 = relu(x1 @ fc1a^T + b) -> V2 region
    gemm_nt<128, 128, 4, 4><<<dim3(6, 128, 1), 256, 0, stream>>>(
        X1, WF1A, QKVX + 1536, bf1a, 768, 768, 768, 3072,
        1, 0, 0, 0, 0, 0, 0, 1.0f, 1);

    // ffn = h1 @ fc1b^T + b -> XR region
    gemm_nt<128, 128, 4, 4><<<dim3(6, 128, 1), 256, 0, stream>>>(
        QKVX + 1536, WF1B, QKVX + 2304, bf1b, 768, 3072, 768, 3072,
        1, 0, 0, 0, 0, 0, 0, 1.0f, 0);

    // x2 = LN(x1 + ffn), in-place over ffn region
    ln_kernel<<<16384, 192, 0, stream>>>(X1, 768, QKVX + 2304, 3072,
                                         QKVX + 2304, 3072, lng, lnb);

    // out = (sum_s x2) @ fc2^T + b
    reduce_stage1_kernel<<<dim3(32, 16), 256, 0, stream>>>(QKVX + 2304, PART);
    reduce_fc2_stage2_kernel<<<32, 256, 0, stream>>>(PART, wfc2, bfc2, out);
}